// Round 13
// baseline (442.802 us; speedup 1.0000x reference)
//
#include <hip/hip_runtime.h>
#include <hip/hip_bf16.h>

#define DD 128

typedef short bf16x8 __attribute__((ext_vector_type(8)));
typedef float f32x4 __attribute__((ext_vector_type(4)));
typedef float f32x2v __attribute__((ext_vector_type(2)));

__device__ __forceinline__ unsigned short f2b(float f) {
  unsigned int u = __float_as_uint(f);
  u = u + 0x7FFFu + ((u >> 16) & 1u);
  return (unsigned short)(u >> 16);
}

// async global->LDS 16B: per-lane global src, wave-uniform LDS dest (+lane*16)
#define GLDS16(gp, lp) __builtin_amdgcn_global_load_lds( \
    (const __attribute__((address_space(1))) unsigned int*)(const void*)(gp), \
    (__attribute__((address_space(3))) unsigned int*)(void*)(lp), 16, 0, 0)

// raw barriers with explicit counted waits (T3/T4): never drain vmcnt to 0 mid-loop
#define BAR_LGKM() do { \
    asm volatile("s_waitcnt lgkmcnt(0)" ::: "memory"); \
    __builtin_amdgcn_sched_barrier(0); \
    __builtin_amdgcn_s_barrier(); } while (0)
#define BAR_VM(nn) do { \
    asm volatile("s_waitcnt vmcnt(" #nn ") lgkmcnt(0)" ::: "memory"); \
    __builtin_amdgcn_sched_barrier(0); \
    __builtin_amdgcn_s_barrier(); } while (0)

// ---------------- x f32 -> bf16 ----------------
__global__ __launch_bounds__(256) void cvt_x_kernel(const float* __restrict__ x,
                                                    unsigned short* __restrict__ xb, int n4) {
  const int i = blockIdx.x * 256 + threadIdx.x;
  if (i < n4) {
    const float4 v = reinterpret_cast<const float4*>(x)[i];
    ushort4 o;
    o.x = f2b(v.x); o.y = f2b(v.y); o.z = f2b(v.z); o.w = f2b(v.w);
    reinterpret_cast<ushort4*>(xb)[i] = o;
  }
}

// ---------------- per-node in-degree ----------------
__global__ void count_kernel(const int* __restrict__ ei, int* __restrict__ cnt, int E) {
  int i = blockIdx.x * blockDim.x + threadIdx.x;
  if (i < E) atomicAdd(&cnt[ei[E + i]], 1);
}

// ---------------- prefix scan (3 kernels) ----------------
__global__ __launch_bounds__(256) void scan_a(const int* __restrict__ cnt,
                                              int* __restrict__ off,
                                              int* __restrict__ bsum, int N) {
  __shared__ int wsum[4];
  const int t = threadIdx.x;
  const int i0 = blockIdx.x * 1024 + t * 4;
  int4 v = {0, 0, 0, 0};
  if (i0 + 3 < N) v = *reinterpret_cast<const int4*>(cnt + i0);
  else {
    if (i0 < N)     v.x = cnt[i0];
    if (i0 + 1 < N) v.y = cnt[i0 + 1];
    if (i0 + 2 < N) v.z = cnt[i0 + 2];
    if (i0 + 3 < N) v.w = cnt[i0 + 3];
  }
  const int s1 = v.x, s2 = s1 + v.y, s3 = s2 + v.z, tot = s3 + v.w;
  const int lane = t & 63, wv = t >> 6;
  int sc = tot;
#pragma unroll
  for (int d = 1; d < 64; d <<= 1) {
    int u = __shfl_up(sc, d);
    if (lane >= d) sc += u;
  }
  if (lane == 63) wsum[wv] = sc;
  __syncthreads();
  int wpre = 0;
  for (int w = 0; w < wv; ++w) wpre += wsum[w];
  const int excl = wpre + sc - tot;
  if (i0 < N)     off[i0]     = excl;
  if (i0 + 1 < N) off[i0 + 1] = excl + s1;
  if (i0 + 2 < N) off[i0 + 2] = excl + s2;
  if (i0 + 3 < N) off[i0 + 3] = excl + s3;
  if (t == 255) bsum[blockIdx.x] = wpre + sc;
}

__global__ void scan_b(int* __restrict__ bsum, int B) {
  const int t = threadIdx.x;
  const int v0 = (t < B) ? bsum[t] : 0;
  int v = v0;
#pragma unroll
  for (int d = 1; d < 64; d <<= 1) {
    int u = __shfl_up(v, d);
    if (t >= d) v += u;
  }
  if (t < B) bsum[t] = v - v0;
}

__global__ __launch_bounds__(256) void scan_c(int* __restrict__ off, int* __restrict__ cur,
                                              const int* __restrict__ bsum, int N, int E) {
  const int t = threadIdx.x;
  const int add = bsum[blockIdx.x];
  const int i0 = blockIdx.x * 1024 + t * 4;
#pragma unroll
  for (int k = 0; k < 4; ++k) {
    const int i = i0 + k;
    if (i < N) {
      const int o = off[i] + add;
      off[i] = o;
      cur[i] = o;
    }
  }
  if (blockIdx.x == 0 && t == 0) off[N] = E;
}

__global__ void fill_kernel(const int* __restrict__ ei, int* __restrict__ cur,
                            int* __restrict__ perm, int E) {
  int i = blockIdx.x * blockDim.x + threadIdx.x;
  if (i < E) {
    const int d = ei[E + i];
    const int pos = atomicAdd(&cur[d], 1);
    perm[pos] = i;
  }
}

// ---------------- edge MLP: T3/T4 software-pipelined, counted vmcnt ----------------
// Tile = 32 edges; E % 32 == 0 (600000 = 18750*32). Double-buffered GLDS16 staging.
__global__ __launch_bounds__(256, 2) void edge_mlp_kernel(
    const unsigned short* __restrict__ xb,   // [N][128] bf16
    const int* __restrict__ ei,              // [2][E]
    const float* __restrict__ ea,            // [E][128] f32
    const float* __restrict__ We1,
    const float* __restrict__ be1,
    const float* __restrict__ We2,
    const float* __restrict__ be2,
    float* __restrict__ e_out,               // [E][128] f32
    int E)
{
  // chunk-swizzled: LDS[r][chunk j] holds global chunk j^(r&7); reads apply same XOR.
  __shared__ __align__(16) unsigned short xs_lds[2][32][128];  // 16 KB
  __shared__ __align__(16) unsigned short xd_lds[2][32][128];  // 16 KB
  __shared__ __align__(16) float          ea_lds[2][32][128];  // 32 KB (staged as f32)
  __shared__ __align__(16) unsigned short h_lds[32][136];      // 8.7 KB (r3 layout)
  __shared__ int sidx[2][64];                                  // [buf][0..31]=src, [32..63]=dst

  const int tid  = threadIdx.x;
  const int wv   = tid >> 6;
  const int lane = tid & 63;
  const int lg   = lane >> 4;
  const int lm   = lane & 15;

  // ---- weight fragments in registers (r3 exact) ----
  bf16x8 w1f[12][2];
  bf16x8 w2f[4][2];
  float b1[2], b2[2];
#pragma unroll
  for (int nf = 0; nf < 2; ++nf) {
    const int n = wv * 32 + nf * 16 + lm;
    b1[nf] = be1[n];
    b2[nf] = be2[n];
#pragma unroll
    for (int kb = 0; kb < 12; ++kb) {
      bf16x8 f;
#pragma unroll
      for (int j = 0; j < 8; ++j)
        f[j] = (short)f2b(We1[(kb * 32 + lg * 8 + j) * DD + n]);
      w1f[kb][nf] = f;
    }
#pragma unroll
    for (int kb = 0; kb < 4; ++kb) {
      bf16x8 f;
#pragma unroll
      for (int j = 0; j < 8; ++j)
        f[j] = (short)f2b(We2[(kb * 32 + lg * 8 + j) * DD + n]);
      w2f[kb][nf] = f;
    }
  }

  const int ntiles = E >> 5;          // 18750
  const int stride = gridDim.x;
  const int bid    = blockIdx.x;

  // Issue one tile's staging: 8 GLDS16 per wave (2 xs + 2 xd + 4 ea)
  auto ISSUE = [&](int tt, int bi) {
    const int eb = tt << 5;
#pragma unroll
    for (int wl = 0; wl < 2; ++wl) {
      const int r0 = wv * 8 + wl * 4;        // 4 bf16 rows per GLDS16
      const int r  = r0 + (lane >> 4);
      const int ch = (lane & 15) ^ (r & 7);
      GLDS16(xb + (size_t)sidx[bi][r] * DD + ch * 8,      &xs_lds[bi][r0][0]);
      GLDS16(xb + (size_t)sidx[bi][32 + r] * DD + ch * 8, &xd_lds[bi][r0][0]);
    }
#pragma unroll
    for (int wl = 0; wl < 4; ++wl) {
      const int r0 = wv * 8 + wl * 2;        // 2 f32 rows per GLDS16
      const int r  = r0 + (lane >> 5);
      const int ch = (lane & 31) ^ (r & 7);
      GLDS16(ea + (size_t)(eb + r) * DD + ch * 4, &ea_lds[bi][r0][0]);
    }
  };

  // ---- prologue: indices for tiles 0,1; stage tile 0 ----
  {
    const int t0 = bid, t1 = bid + stride;
    if (tid < 64) {
      if (t0 < ntiles) {
        const int eb = t0 << 5;
        sidx[0][tid] = (tid < 32) ? ei[eb + tid] : ei[E + eb + tid - 32];
      }
      if (t1 < ntiles) {
        const int eb = t1 << 5;
        sidx[1][tid] = (tid < 32) ? ei[eb + tid] : ei[E + eb + tid - 32];
      }
    }
  }
  BAR_LGKM();
  if (bid < ntiles) ISSUE(bid, 0);
  BAR_VM(0);

  for (int i = 0; ; ++i) {
    const int t = bid + i * stride;
    if (t >= ntiles) break;
    const int b  = i & 1;
    const int eb = t << 5;
    const int tn = t + stride;
    const int t2 = t + 2 * stride;

    // ---- B: prefetch idx(t+2) into a register (issued before GLDS16s) ----
    int idxreg = 0;
    const bool h2 = (t2 < ntiles) && (tid < 64);
    if (h2) {
      const int e2 = t2 << 5;
      idxreg = (tid < 32) ? ei[e2 + tid] : ei[E + e2 + tid - 32];
    }

    // ---- A: issue next tile's staging into the other buffer ----
    if (tn < ntiles) ISSUE(tn, b ^ 1);

    // ---- C: layer 1 on tile t (buf b): acc = [xs|xd|ea] @ We1 ----
    f32x4 acc[2][2];
#pragma unroll
    for (int mf = 0; mf < 2; ++mf)
#pragma unroll
      for (int nf = 0; nf < 2; ++nf)
        acc[mf][nf] = (f32x4){0.f, 0.f, 0.f, 0.f};

#pragma unroll
    for (int kb = 0; kb < 12; ++kb) {
      bf16x8 a[2];
      if (kb < 8) {
        const unsigned short (*blk)[128] = (kb < 4) ? xs_lds[b] : xd_lds[b];
        const int kl = kb & 3;
#pragma unroll
        for (int mf = 0; mf < 2; ++mf) {
          const int r = mf * 16 + lm;
          a[mf] = *reinterpret_cast<const bf16x8*>(&blk[r][((kl * 4 + lg) ^ (r & 7)) * 8]);
        }
      } else {
        const int c0 = (kb - 8) * 8 + lg * 2;
#pragma unroll
        for (int mf = 0; mf < 2; ++mf) {
          const int r  = mf * 16 + lm;
          const int sw = r & 7;
          const f32x4 lo = *reinterpret_cast<const f32x4*>(&ea_lds[b][r][(c0 ^ sw) * 4]);
          const f32x4 hi = *reinterpret_cast<const f32x4*>(&ea_lds[b][r][((c0 + 1) ^ sw) * 4]);
          bf16x8 o;
          o[0] = (short)f2b(lo[0]); o[1] = (short)f2b(lo[1]);
          o[2] = (short)f2b(lo[2]); o[3] = (short)f2b(lo[3]);
          o[4] = (short)f2b(hi[0]); o[5] = (short)f2b(hi[1]);
          o[6] = (short)f2b(hi[2]); o[7] = (short)f2b(hi[3]);
          a[mf] = o;
        }
      }
#pragma unroll
      for (int mf = 0; mf < 2; ++mf)
#pragma unroll
        for (int nf = 0; nf < 2; ++nf)
          acc[mf][nf] = __builtin_amdgcn_mfma_f32_16x16x32_bf16(a[mf], w1f[kb][nf], acc[mf][nf], 0, 0, 0);
    }

    // ---- h = relu(acc + b1) -> h_lds (r3 layout) ----
#pragma unroll
    for (int mf = 0; mf < 2; ++mf)
#pragma unroll
      for (int nf = 0; nf < 2; ++nf)
#pragma unroll
        for (int rg = 0; rg < 4; ++rg) {
          const int m = mf * 16 + lg * 4 + rg;
          const int n = wv * 32 + nf * 16 + lm;
          float v = acc[mf][nf][rg] + b1[nf];
          h_lds[m][n] = f2b(v > 0.f ? v : 0.f);
        }
    BAR_LGKM();   // h visible; all buf[b] reads complete (data-dep ordered before h)

    // ---- D: park idx(t+2) into sidx[i&1] (its last reader finished at iter i-1) ----
    if (h2) sidx[b][tid] = idxreg;

    // ---- E: layer 2 + NT stores (exactly 16 store instrs per wave, issued last) ----
    f32x4 acc2[2][2];
#pragma unroll
    for (int mf = 0; mf < 2; ++mf)
#pragma unroll
      for (int nf = 0; nf < 2; ++nf)
        acc2[mf][nf] = (f32x4){0.f, 0.f, 0.f, 0.f};

#pragma unroll
    for (int kb = 0; kb < 4; ++kb) {
      bf16x8 a[2];
#pragma unroll
      for (int mf = 0; mf < 2; ++mf)
        a[mf] = *reinterpret_cast<const bf16x8*>(&h_lds[mf * 16 + lm][kb * 32 + lg * 8]);
#pragma unroll
      for (int mf = 0; mf < 2; ++mf)
#pragma unroll
        for (int nf = 0; nf < 2; ++nf)
          acc2[mf][nf] = __builtin_amdgcn_mfma_f32_16x16x32_bf16(a[mf], w2f[kb][nf], acc2[mf][nf], 0, 0, 0);
    }

#pragma unroll
    for (int mf = 0; mf < 2; ++mf)
#pragma unroll
      for (int rg = 0; rg < 4; ++rg) {
        const int gm = eb + mf * 16 + lg * 4 + rg;
#pragma unroll
        for (int nf = 0; nf < 2; ++nf) {
          const int n = wv * 32 + nf * 16 + lm;
          __builtin_nontemporal_store(acc2[mf][nf][rg] + b2[nf],
                                      &e_out[(size_t)gm * DD + n]);
        }
      }

    // ---- F: wait ONLY for t+1's 8 staging loads (16 stores issued after them) ----
    BAR_VM(16);
  }
}

// ---------------- CSR scatter-mean: wave per node, 8-deep batched NT gathers ----
__global__ __launch_bounds__(256) void agg_kernel(const float* __restrict__ e_out,
                                                  const int* __restrict__ off,
                                                  const int* __restrict__ perm,
                                                  float* __restrict__ agg, int N) {
  const int wv   = threadIdx.x >> 6;
  const int lane = threadIdx.x & 63;
  const int nid  = blockIdx.x * 4 + wv;
  if (nid >= N) return;
  const int o0 = off[nid], o1 = off[nid + 1];
  float sx = 0.f, sy = 0.f;
  int j = o0;
  for (; j + 8 <= o1; j += 8) {
    int r[8];
#pragma unroll
    for (int k = 0; k < 8; ++k) r[k] = perm[j + k];
    f32x2v v[8];
#pragma unroll
    for (int k = 0; k < 8; ++k)
      v[k] = __builtin_nontemporal_load(
          reinterpret_cast<const f32x2v*>(e_out + (size_t)r[k] * DD + (lane << 1)));
#pragma unroll
    for (int k = 0; k < 8; ++k) { sx += v[k][0]; sy += v[k][1]; }
  }
  if (j + 4 <= o1) {
    int r[4];
#pragma unroll
    for (int k = 0; k < 4; ++k) r[k] = perm[j + k];
    f32x2v v[4];
#pragma unroll
    for (int k = 0; k < 4; ++k)
      v[k] = __builtin_nontemporal_load(
          reinterpret_cast<const f32x2v*>(e_out + (size_t)r[k] * DD + (lane << 1)));
#pragma unroll
    for (int k = 0; k < 4; ++k) { sx += v[k][0]; sy += v[k][1]; }
    j += 4;
  }
  for (; j < o1; ++j) {
    const int r = perm[j];
    const f32x2v v = __builtin_nontemporal_load(
        reinterpret_cast<const f32x2v*>(e_out + (size_t)r * DD + (lane << 1)));
    sx += v[0]; sy += v[1];
  }
  const int deg = o1 - o0;
  const float inv = deg > 0 ? 1.f / (float)deg : 0.f;
  float2 o;
  o.x = sx * inv;
  o.y = sy * inv;
  *reinterpret_cast<float2*>(agg + (size_t)nid * DD + (lane << 1)) = o;
}

// ---------------- node MLP (r11 exact) ----------------
__global__ __launch_bounds__(256, 2) void node_mlp_kernel(
    const float* __restrict__ x,
    const float* __restrict__ Wn1,
    const float* __restrict__ bn1,
    const float* __restrict__ Wn2,
    const float* __restrict__ bn2,
    float* __restrict__ xout,        // in: agg mean, out: x_out
    int N)
{
  __shared__ __align__(16) unsigned short A_lds[64][264];
  __shared__ __align__(16) unsigned short h_lds[64][136];

  const int tid  = threadIdx.x;
  const int wv   = tid >> 6;
  const int lane = tid & 63;
  const int lg   = lane >> 4;
  const int lm   = lane & 15;

  bf16x8 w1f[8][2];
  bf16x8 w2f[4][2];
  float b1[2], b2[2];
#pragma unroll
  for (int nf = 0; nf < 2; ++nf) {
    const int n = wv * 32 + nf * 16 + lm;
    b1[nf] = bn1[n];
    b2[nf] = bn2[n];
#pragma unroll
    for (int kb = 0; kb < 8; ++kb) {
      bf16x8 f;
#pragma unroll
      for (int j = 0; j < 8; ++j)
        f[j] = (short)f2b(Wn1[(kb * 32 + lg * 8 + j) * DD + n]);
      w1f[kb][nf] = f;
    }
#pragma unroll
    for (int kb = 0; kb < 4; ++kb) {
      bf16x8 f;
#pragma unroll
      for (int j = 0; j < 8; ++j)
        f[j] = (short)f2b(Wn2[(kb * 32 + lg * 8 + j) * DD + n]);
      w2f[kb][nf] = f;
    }
  }

  const int ntiles = (N + 63) >> 6;
  for (int tile = blockIdx.x; tile < ntiles; tile += gridDim.x) {
    const int nbase = tile << 6;
    __syncthreads();

#pragma unroll
    for (int it = 0; it < 16; ++it) {
      const int q = tid + it * 256;
      const int r = q >> 6;
      const int c = q & 63;
      int gr = nbase + r;
      if (gr >= N) gr = N - 1;
      float4 v;
      if (c < 32) v = *reinterpret_cast<const float4*>(x + (size_t)gr * DD + (c << 2));
      else        v = *reinterpret_cast<const float4*>(xout + (size_t)gr * DD + ((c - 32) << 2));
      unsigned short* dst = &A_lds[r][c << 2];
      dst[0] = f2b(v.x); dst[1] = f2b(v.y); dst[2] = f2b(v.z); dst[3] = f2b(v.w);
    }
    __syncthreads();

    f32x4 acc[4][2];
#pragma unroll
    for (int mf = 0; mf < 4; ++mf)
#pragma unroll
      for (int nf = 0; nf < 2; ++nf)
        acc[mf][nf] = (f32x4){0.f, 0.f, 0.f, 0.f};

#pragma unroll
    for (int kb = 0; kb < 8; ++kb) {
      bf16x8 a[4];
#pragma unroll
      for (int mf = 0; mf < 4; ++mf)
        a[mf] = *reinterpret_cast<const bf16x8*>(&A_lds[mf * 16 + lm][kb * 32 + lg * 8]);
#pragma unroll
      for (int mf = 0; mf < 4; ++mf)
#pragma unroll
        for (int nf = 0; nf < 2; ++nf)
          acc[mf][nf] = __builtin_amdgcn_mfma_f32_16x16x32_bf16(a[mf], w1f[kb][nf], acc[mf][nf], 0, 0, 0);
    }

#pragma unroll
    for (int mf = 0; mf < 4; ++mf)
#pragma unroll
      for (int nf = 0; nf < 2; ++nf)
#pragma unroll
        for (int rg = 0; rg < 4; ++rg) {
          const int m = mf * 16 + lg * 4 + rg;
          const int n = wv * 32 + nf * 16 + lm;
          float v = acc[mf][nf][rg] + b1[nf];
          h_lds[m][n] = f2b(v > 0.f ? v : 0.f);
        }
    __syncthreads();

    f32x4 acc2[4][2];
#pragma unroll
    for (int mf = 0; mf < 4; ++mf)
#pragma unroll
      for (int nf = 0; nf < 2; ++nf)
        acc2[mf][nf] = (f32x4){0.f, 0.f, 0.f, 0.f};

#pragma unroll
    for (int kb = 0; kb < 4; ++kb) {
      bf16x8 a[4];
#pragma unroll
      for (int mf = 0; mf < 4; ++mf)
        a[mf] = *reinterpret_cast<const bf16x8*>(&h_lds[mf * 16 + lm][kb * 32 + lg * 8]);
#pragma unroll
      for (int mf = 0; mf < 4; ++mf)
#pragma unroll
        for (int nf = 0; nf < 2; ++nf)
          acc2[mf][nf] = __builtin_amdgcn_mfma_f32_16x16x32_bf16(a[mf], w2f[kb][nf], acc2[mf][nf], 0, 0, 0);
    }

#pragma unroll
    for (int mf = 0; mf < 4; ++mf)
#pragma unroll
      for (int rg = 0; rg < 4; ++rg) {
        const int gm = nbase + mf * 16 + lg * 4 + rg;
        if (gm < N) {
#pragma unroll
          for (int nf = 0; nf < 2; ++nf) {
            const int n = wv * 32 + nf * 16 + lm;
            xout[(size_t)gm * DD + n] = acc2[mf][nf][rg] + b2[nf];
          }
        }
      }
  }
}

extern "C" void kernel_launch(void* const* d_in, const int* in_sizes, int n_in,
                              void* d_out, int out_size, void* d_ws, size_t ws_size,
                              hipStream_t stream) {
  const float* x   = (const float*)d_in[0];
  const int*   ei  = (const int*)d_in[1];
  const float* ea  = (const float*)d_in[2];
  const float* We1 = (const float*)d_in[3];
  const float* be1 = (const float*)d_in[4];
  const float* We2 = (const float*)d_in[5];
  const float* be2 = (const float*)d_in[6];
  const float* Wn1 = (const float*)d_in[7];
  const float* bn1 = (const float*)d_in[8];
  const float* Wn2 = (const float*)d_in[9];
  const float* bn2 = (const float*)d_in[10];

  const int N = in_sizes[0] / DD;   // 50000
  const int E = in_sizes[2] / DD;   // 600000

  float* out   = (float*)d_out;
  float* xout  = out;                    // x_out; early: x_bf16 scratch, then agg mean
  float* e_out = out + (size_t)N * DD;   // e output

  unsigned short* xb = (unsigned short*)xout;  // x as bf16 (dead after edge kernel)

  int* cnt  = (int*)d_ws;                // N
  int* off  = cnt + N;                   // N+1
  int* cur  = off + N + 1;               // N
  int* perm = cur + N;                   // E
  int* bsum = perm + E;                  // <=64

  const int SCAN_B = (N + 1023) / 1024;  // 49

  hipMemsetAsync(cnt, 0, (size_t)N * sizeof(int), stream);

  cvt_x_kernel<<<(N * DD / 4 + 255) / 256, 256, 0, stream>>>(x, xb, N * DD / 4);

  count_kernel<<<(E + 255) / 256, 256, 0, stream>>>(ei, cnt, E);
  scan_a<<<SCAN_B, 256, 0, stream>>>(cnt, off, bsum, N);
  scan_b<<<1, 64, 0, stream>>>(bsum, SCAN_B);
  scan_c<<<SCAN_B, 256, 0, stream>>>(off, cur, bsum, N, E);
  fill_kernel<<<(E + 255) / 256, 256, 0, stream>>>(ei, cur, perm, E);

  edge_mlp_kernel<<<2048, 256, 0, stream>>>(xb, ei, ea, We1, be1, We2, be2, e_out, E);

  agg_kernel<<<(N + 3) / 4, 256, 0, stream>>>(e_out, off, perm, xout, N);

  const int node_tiles = (N + 63) / 64;
  node_mlp_kernel<<<node_tiles, 256, 0, stream>>>(x, Wn1, bn1, Wn2, bn2, xout, N);
}

// Round 14
// 376.677 us; speedup vs baseline: 1.1755x; 1.1755x over previous
//
#include <hip/hip_runtime.h>
#include <hip/hip_bf16.h>

#define DD 128

typedef short bf16x8 __attribute__((ext_vector_type(8)));
typedef float f32x4 __attribute__((ext_vector_type(4)));
typedef float f32x2v __attribute__((ext_vector_type(2)));

__device__ __forceinline__ unsigned short f2b(float f) {
  unsigned int u = __float_as_uint(f);
  u = u + 0x7FFFu + ((u >> 16) & 1u);
  return (unsigned short)(u >> 16);
}

// async global->LDS 16B: per-lane global src, wave-uniform LDS dest (+lane*16)
#define GLDS16(gp, lp) __builtin_amdgcn_global_load_lds( \
    (const __attribute__((address_space(1))) unsigned int*)(const void*)(gp), \
    (__attribute__((address_space(3))) unsigned int*)(void*)(lp), 16, 0, 0)

// ---------------- fused: x f32 -> bf16  (blocks [0, cvtB)) + in-degree count ----
__global__ __launch_bounds__(256) void cvt_count_kernel(
    const float* __restrict__ x, unsigned short* __restrict__ xb, int n4, int cvtB,
    const int* __restrict__ ei, int* __restrict__ cnt, int E) {
  if (blockIdx.x < (unsigned)cvtB) {
    const int i = blockIdx.x * 256 + threadIdx.x;
    if (i < n4) {
      const f32x4 v = __builtin_nontemporal_load(
          reinterpret_cast<const f32x4*>(x) + i);
      ushort4 o;
      o.x = f2b(v[0]); o.y = f2b(v[1]); o.z = f2b(v[2]); o.w = f2b(v[3]);
      reinterpret_cast<ushort4*>(xb)[i] = o;
    }
  } else {
    const int i = (blockIdx.x - cvtB) * 256 + threadIdx.x;
    if (i < E) atomicAdd(&cnt[ei[E + i]], 1);
  }
}

// ---------------- prefix scan (3 kernels) ----------------
__global__ __launch_bounds__(256) void scan_a(const int* __restrict__ cnt,
                                              int* __restrict__ off,
                                              int* __restrict__ bsum, int N) {
  __shared__ int wsum[4];
  const int t = threadIdx.x;
  const int i0 = blockIdx.x * 1024 + t * 4;
  int4 v = {0, 0, 0, 0};
  if (i0 + 3 < N) v = *reinterpret_cast<const int4*>(cnt + i0);
  else {
    if (i0 < N)     v.x = cnt[i0];
    if (i0 + 1 < N) v.y = cnt[i0 + 1];
    if (i0 + 2 < N) v.z = cnt[i0 + 2];
    if (i0 + 3 < N) v.w = cnt[i0 + 3];
  }
  const int s1 = v.x, s2 = s1 + v.y, s3 = s2 + v.z, tot = s3 + v.w;
  const int lane = t & 63, wv = t >> 6;
  int sc = tot;
#pragma unroll
  for (int d = 1; d < 64; d <<= 1) {
    int u = __shfl_up(sc, d);
    if (lane >= d) sc += u;
  }
  if (lane == 63) wsum[wv] = sc;
  __syncthreads();
  int wpre = 0;
  for (int w = 0; w < wv; ++w) wpre += wsum[w];
  const int excl = wpre + sc - tot;
  if (i0 < N)     off[i0]     = excl;
  if (i0 + 1 < N) off[i0 + 1] = excl + s1;
  if (i0 + 2 < N) off[i0 + 2] = excl + s2;
  if (i0 + 3 < N) off[i0 + 3] = excl + s3;
  if (t == 255) bsum[blockIdx.x] = wpre + sc;
}

__global__ void scan_b(int* __restrict__ bsum, int B) {
  const int t = threadIdx.x;
  const int v0 = (t < B) ? bsum[t] : 0;
  int v = v0;
#pragma unroll
  for (int d = 1; d < 64; d <<= 1) {
    int u = __shfl_up(v, d);
    if (t >= d) v += u;
  }
  if (t < B) bsum[t] = v - v0;
}

__global__ __launch_bounds__(256) void scan_c(int* __restrict__ off, int* __restrict__ cur,
                                              const int* __restrict__ bsum, int N, int E) {
  const int t = threadIdx.x;
  const int add = bsum[blockIdx.x];
  const int i0 = blockIdx.x * 1024 + t * 4;
#pragma unroll
  for (int k = 0; k < 4; ++k) {
    const int i = i0 + k;
    if (i < N) {
      const int o = off[i] + add;
      off[i] = o;
      cur[i] = o;
    }
  }
  if (blockIdx.x == 0 && t == 0) off[N] = E;
}

__global__ void fill_kernel(const int* __restrict__ ei, int* __restrict__ cur,
                            int* __restrict__ perm, int E) {
  int i = blockIdx.x * blockDim.x + threadIdx.x;
  if (i < E) {
    const int d = ei[E + i];
    const int pos = atomicAdd(&cur[d], 1);
    perm[pos] = i;
  }
}

// ---------------- edge MLP: r3/r11 body + nontemporal stream hints (r12 exact) ----
// E is a multiple of 64 (600000 = 9375*64) — no tail handling.
__global__ __launch_bounds__(256, 2) void edge_mlp_kernel(
    const unsigned short* __restrict__ xb,   // [N][128] bf16
    const int* __restrict__ ei,              // [2][E]
    const float* __restrict__ ea,            // [E][128] f32
    const float* __restrict__ We1,
    const float* __restrict__ be1,
    const float* __restrict__ We2,
    const float* __restrict__ be2,
    float* __restrict__ e_out,               // [E][128] f32
    int E)
{
  // x blocks are staged by global_load_lds (linear dest, pre-swizzled source):
  // LDS[r][chunk j] holds global chunk (j ^ (r&7)); reads apply the same XOR.
  __shared__ __align__(16) unsigned short xs_lds[64][128];
  __shared__ __align__(16) unsigned short xd_lds[64][128];
  __shared__ __align__(16) unsigned short ea_lds[64][128];
  __shared__ __align__(16) unsigned short h_lds[64][136];
  __shared__ int srcs[64], dsts[64];

  const int tid  = threadIdx.x;
  const int wv   = tid >> 6;
  const int lane = tid & 63;
  const int lg   = lane >> 4;
  const int lm   = lane & 15;

  // ---- weight fragments in registers ----
  bf16x8 w1f[12][2];
  bf16x8 w2f[4][2];
  float b1[2], b2[2];
#pragma unroll
  for (int nf = 0; nf < 2; ++nf) {
    const int n = wv * 32 + nf * 16 + lm;
    b1[nf] = be1[n];
    b2[nf] = be2[n];
#pragma unroll
    for (int kb = 0; kb < 12; ++kb) {
      bf16x8 f;
#pragma unroll
      for (int j = 0; j < 8; ++j)
        f[j] = (short)f2b(We1[(kb * 32 + lg * 8 + j) * DD + n]);
      w1f[kb][nf] = f;
    }
#pragma unroll
    for (int kb = 0; kb < 4; ++kb) {
      bf16x8 f;
#pragma unroll
      for (int j = 0; j < 8; ++j)
        f[j] = (short)f2b(We2[(kb * 32 + lg * 8 + j) * DD + n]);
      w2f[kb][nf] = f;
    }
  }

  const int ntiles = E >> 6;
  for (int tile = blockIdx.x; tile < ntiles; tile += gridDim.x) {
    const int ebase = tile << 6;
    __syncthreads();  // previous tile's LDS readers done

    // ---- preload this tile's 128 indices ----
    if (tid < 64)       srcs[tid]      = ei[ebase + tid];
    else if (tid < 128) dsts[tid - 64] = ei[E + ebase + tid - 64];
    __syncthreads();

    // ---- async x gathers: each wave stages 16 rows of xs and xd ----
    {
#pragma unroll
      for (int wl = 0; wl < 4; ++wl) {
        const int r0 = wv * 16 + wl * 4;
        const int r  = r0 + (lane >> 4);
        const int ch = (lane & 15) ^ (r & 7);
        GLDS16(xb + (size_t)srcs[r] * DD + ch * 8, &xs_lds[r0][0]);
        GLDS16(xb + (size_t)dsts[r] * DD + ch * 8, &xd_lds[r0][0]);
      }
    }

    // ---- ea: nontemporal f32 stream -> bf16 -> swizzled b128 LDS writes ----
    {
      f32x4 va[4], vb[4];
#pragma unroll
      for (int it = 0; it < 4; ++it) {
        const int q = tid + it * 256;
        const int r = q >> 4;
        const int c = q & 15;
        const float* p = ea + (size_t)(ebase + r) * DD + c * 8;
        va[it] = __builtin_nontemporal_load(reinterpret_cast<const f32x4*>(p));
        vb[it] = __builtin_nontemporal_load(reinterpret_cast<const f32x4*>(p + 4));
      }
#pragma unroll
      for (int it = 0; it < 4; ++it) {
        const int q = tid + it * 256;
        const int r = q >> 4;
        const int c = q & 15;
        bf16x8 o;
        o[0] = (short)f2b(va[it][0]); o[1] = (short)f2b(va[it][1]);
        o[2] = (short)f2b(va[it][2]); o[3] = (short)f2b(va[it][3]);
        o[4] = (short)f2b(vb[it][0]); o[5] = (short)f2b(vb[it][1]);
        o[6] = (short)f2b(vb[it][2]); o[7] = (short)f2b(vb[it][3]);
        *reinterpret_cast<bf16x8*>(&ea_lds[r][(c ^ (r & 7)) * 8]) = o;
      }
    }
    __syncthreads();  // drains vmcnt (incl. global_load_lds) + lgkm

    // ---- layer 1: h = relu(A @ We1 + be1), K = 384 ----
    f32x4 acc[4][2];
#pragma unroll
    for (int mf = 0; mf < 4; ++mf)
#pragma unroll
      for (int nf = 0; nf < 2; ++nf)
        acc[mf][nf] = (f32x4){0.f, 0.f, 0.f, 0.f};

#pragma unroll
    for (int kb = 0; kb < 12; ++kb) {
      const unsigned short (*blk)[128] = (kb < 4) ? xs_lds : (kb < 8) ? xd_lds : ea_lds;
      const int kl = kb & 3;
      bf16x8 a[4];
#pragma unroll
      for (int mf = 0; mf < 4; ++mf) {
        const int r = mf * 16 + lm;
        a[mf] = *reinterpret_cast<const bf16x8*>(&blk[r][((kl * 4 + lg) ^ (r & 7)) * 8]);
      }
#pragma unroll
      for (int mf = 0; mf < 4; ++mf)
#pragma unroll
        for (int nf = 0; nf < 2; ++nf)
          acc[mf][nf] = __builtin_amdgcn_mfma_f32_16x16x32_bf16(a[mf], w1f[kb][nf], acc[mf][nf], 0, 0, 0);
    }

#pragma unroll
    for (int mf = 0; mf < 4; ++mf)
#pragma unroll
      for (int nf = 0; nf < 2; ++nf)
#pragma unroll
        for (int rg = 0; rg < 4; ++rg) {
          const int m = mf * 16 + lg * 4 + rg;
          const int n = wv * 32 + nf * 16 + lm;
          float v = acc[mf][nf][rg] + b1[nf];
          h_lds[m][n] = f2b(v > 0.f ? v : 0.f);
        }
    __syncthreads();

    // ---- layer 2: e = h @ We2 + be2 ----
    f32x4 acc2[4][2];
#pragma unroll
    for (int mf = 0; mf < 4; ++mf)
#pragma unroll
      for (int nf = 0; nf < 2; ++nf)
        acc2[mf][nf] = (f32x4){0.f, 0.f, 0.f, 0.f};

#pragma unroll
    for (int kb = 0; kb < 4; ++kb) {
      bf16x8 a[4];
#pragma unroll
      for (int mf = 0; mf < 4; ++mf)
        a[mf] = *reinterpret_cast<const bf16x8*>(&h_lds[mf * 16 + lm][kb * 32 + lg * 8]);
#pragma unroll
      for (int mf = 0; mf < 4; ++mf)
#pragma unroll
        for (int nf = 0; nf < 2; ++nf)
          acc2[mf][nf] = __builtin_amdgcn_mfma_f32_16x16x32_bf16(a[mf], w2f[kb][nf], acc2[mf][nf], 0, 0, 0);
    }

    // ---- epilogue: nontemporal e stores (write-once stream) ----
#pragma unroll
    for (int mf = 0; mf < 4; ++mf)
#pragma unroll
      for (int rg = 0; rg < 4; ++rg) {
        const int gm = ebase + mf * 16 + lg * 4 + rg;
#pragma unroll
        for (int nf = 0; nf < 2; ++nf) {
          const int n = wv * 32 + nf * 16 + lm;
          __builtin_nontemporal_store(acc2[mf][nf][rg] + b2[nf],
                                      &e_out[(size_t)gm * DD + n]);
        }
      }
  }
}

// ---------------- CSR scatter-mean: wave per node, 8-deep batched NT gathers ----
__global__ __launch_bounds__(256) void agg_kernel(const float* __restrict__ e_out,
                                                  const int* __restrict__ off,
                                                  const int* __restrict__ perm,
                                                  float* __restrict__ agg, int N) {
  const int wv   = threadIdx.x >> 6;
  const int lane = threadIdx.x & 63;
  const int nid  = blockIdx.x * 4 + wv;
  if (nid >= N) return;
  const int o0 = off[nid], o1 = off[nid + 1];
  float sx = 0.f, sy = 0.f;
  int j = o0;
  for (; j + 8 <= o1; j += 8) {
    int r[8];
#pragma unroll
    for (int k = 0; k < 8; ++k) r[k] = perm[j + k];
    f32x2v v[8];
#pragma unroll
    for (int k = 0; k < 8; ++k)
      v[k] = __builtin_nontemporal_load(
          reinterpret_cast<const f32x2v*>(e_out + (size_t)r[k] * DD + (lane << 1)));
#pragma unroll
    for (int k = 0; k < 8; ++k) { sx += v[k][0]; sy += v[k][1]; }
  }
  if (j + 4 <= o1) {
    int r[4];
#pragma unroll
    for (int k = 0; k < 4; ++k) r[k] = perm[j + k];
    f32x2v v[4];
#pragma unroll
    for (int k = 0; k < 4; ++k)
      v[k] = __builtin_nontemporal_load(
          reinterpret_cast<const f32x2v*>(e_out + (size_t)r[k] * DD + (lane << 1)));
#pragma unroll
    for (int k = 0; k < 4; ++k) { sx += v[k][0]; sy += v[k][1]; }
    j += 4;
  }
  for (; j < o1; ++j) {
    const int r = perm[j];
    const f32x2v v = __builtin_nontemporal_load(
        reinterpret_cast<const f32x2v*>(e_out + (size_t)r * DD + (lane << 1)));
    sx += v[0]; sy += v[1];
  }
  const int deg = o1 - o0;
  const float inv = deg > 0 ? 1.f / (float)deg : 0.f;
  float2 o;
  o.x = sx * inv;
  o.y = sy * inv;
  *reinterpret_cast<float2*>(agg + (size_t)nid * DD + (lane << 1)) = o;
}

// ---------------- node MLP (r11 exact) ----------------
__global__ __launch_bounds__(256, 2) void node_mlp_kernel(
    const float* __restrict__ x,
    const float* __restrict__ Wn1,
    const float* __restrict__ bn1,
    const float* __restrict__ Wn2,
    const float* __restrict__ bn2,
    float* __restrict__ xout,        // in: agg mean, out: x_out
    int N)
{
  __shared__ __align__(16) unsigned short A_lds[64][264];
  __shared__ __align__(16) unsigned short h_lds[64][136];

  const int tid  = threadIdx.x;
  const int wv   = tid >> 6;
  const int lane = tid & 63;
  const int lg   = lane >> 4;
  const int lm   = lane & 15;

  bf16x8 w1f[8][2];
  bf16x8 w2f[4][2];
  float b1[2], b2[2];
#pragma unroll
  for (int nf = 0; nf < 2; ++nf) {
    const int n = wv * 32 + nf * 16 + lm;
    b1[nf] = bn1[n];
    b2[nf] = bn2[n];
#pragma unroll
    for (int kb = 0; kb < 8; ++kb) {
      bf16x8 f;
#pragma unroll
      for (int j = 0; j < 8; ++j)
        f[j] = (short)f2b(Wn1[(kb * 32 + lg * 8 + j) * DD + n]);
      w1f[kb][nf] = f;
    }
#pragma unroll
    for (int kb = 0; kb < 4; ++kb) {
      bf16x8 f;
#pragma unroll
      for (int j = 0; j < 8; ++j)
        f[j] = (short)f2b(Wn2[(kb * 32 + lg * 8 + j) * DD + n]);
      w2f[kb][nf] = f;
    }
  }

  const int ntiles = (N + 63) >> 6;
  for (int tile = blockIdx.x; tile < ntiles; tile += gridDim.x) {
    const int nbase = tile << 6;
    __syncthreads();

#pragma unroll
    for (int it = 0; it < 16; ++it) {
      const int q = tid + it * 256;
      const int r = q >> 6;
      const int c = q & 63;
      int gr = nbase + r;
      if (gr >= N) gr = N - 1;
      float4 v;
      if (c < 32) v = *reinterpret_cast<const float4*>(x + (size_t)gr * DD + (c << 2));
      else        v = *reinterpret_cast<const float4*>(xout + (size_t)gr * DD + ((c - 32) << 2));
      unsigned short* dst = &A_lds[r][c << 2];
      dst[0] = f2b(v.x); dst[1] = f2b(v.y); dst[2] = f2b(v.z); dst[3] = f2b(v.w);
    }
    __syncthreads();

    f32x4 acc[4][2];
#pragma unroll
    for (int mf = 0; mf < 4; ++mf)
#pragma unroll
      for (int nf = 0; nf < 2; ++nf)
        acc[mf][nf] = (f32x4){0.f, 0.f, 0.f, 0.f};

#pragma unroll
    for (int kb = 0; kb < 8; ++kb) {
      bf16x8 a[4];
#pragma unroll
      for (int mf = 0; mf < 4; ++mf)
        a[mf] = *reinterpret_cast<const bf16x8*>(&A_lds[mf * 16 + lm][kb * 32 + lg * 8]);
#pragma unroll
      for (int mf = 0; mf < 4; ++mf)
#pragma unroll
        for (int nf = 0; nf < 2; ++nf)
          acc[mf][nf] = __builtin_amdgcn_mfma_f32_16x16x32_bf16(a[mf], w1f[kb][nf], acc[mf][nf], 0, 0, 0);
    }

#pragma unroll
    for (int mf = 0; mf < 4; ++mf)
#pragma unroll
      for (int nf = 0; nf < 2; ++nf)
#pragma unroll
        for (int rg = 0; rg < 4; ++rg) {
          const int m = mf * 16 + lg * 4 + rg;
          const int n = wv * 32 + nf * 16 + lm;
          float v = acc[mf][nf][rg] + b1[nf];
          h_lds[m][n] = f2b(v > 0.f ? v : 0.f);
        }
    __syncthreads();

    f32x4 acc2[4][2];
#pragma unroll
    for (int mf = 0; mf < 4; ++mf)
#pragma unroll
      for (int nf = 0; nf < 2; ++nf)
        acc2[mf][nf] = (f32x4){0.f, 0.f, 0.f, 0.f};

#pragma unroll
    for (int kb = 0; kb < 4; ++kb) {
      bf16x8 a[4];
#pragma unroll
      for (int mf = 0; mf < 4; ++mf)
        a[mf] = *reinterpret_cast<const bf16x8*>(&h_lds[mf * 16 + lm][kb * 32 + lg * 8]);
#pragma unroll
      for (int mf = 0; mf < 4; ++mf)
#pragma unroll
        for (int nf = 0; nf < 2; ++nf)
          acc2[mf][nf] = __builtin_amdgcn_mfma_f32_16x16x32_bf16(a[mf], w2f[kb][nf], acc2[mf][nf], 0, 0, 0);
    }

#pragma unroll
    for (int mf = 0; mf < 4; ++mf)
#pragma unroll
      for (int rg = 0; rg < 4; ++rg) {
        const int gm = nbase + mf * 16 + lg * 4 + rg;
        if (gm < N) {
#pragma unroll
          for (int nf = 0; nf < 2; ++nf) {
            const int n = wv * 32 + nf * 16 + lm;
            xout[(size_t)gm * DD + n] = acc2[mf][nf][rg] + b2[nf];
          }
        }
      }
  }
}

extern "C" void kernel_launch(void* const* d_in, const int* in_sizes, int n_in,
                              void* d_out, int out_size, void* d_ws, size_t ws_size,
                              hipStream_t stream) {
  const float* x   = (const float*)d_in[0];
  const int*   ei  = (const int*)d_in[1];
  const float* ea  = (const float*)d_in[2];
  const float* We1 = (const float*)d_in[3];
  const float* be1 = (const float*)d_in[4];
  const float* We2 = (const float*)d_in[5];
  const float* be2 = (const float*)d_in[6];
  const float* Wn1 = (const float*)d_in[7];
  const float* bn1 = (const float*)d_in[8];
  const float* Wn2 = (const float*)d_in[9];
  const float* bn2 = (const float*)d_in[10];

  const int N = in_sizes[0] / DD;   // 50000
  const int E = in_sizes[2] / DD;   // 600000

  float* out   = (float*)d_out;
  float* xout  = out;                    // x_out; early: x_bf16 scratch, then agg mean
  float* e_out = out + (size_t)N * DD;   // e output

  unsigned short* xb = (unsigned short*)xout;  // x as bf16 (dead after edge kernel)

  int* cnt  = (int*)d_ws;                // N
  int* off  = cnt + N;                   // N+1
  int* cur  = off + N + 1;               // N
  int* perm = cur + N;                   // E
  int* bsum = perm + E;                  // <=64

  const int SCAN_B = (N + 1023) / 1024;  // 49
  const int n4     = N * DD / 4;         // 1.6M
  const int cvtB   = (n4 + 255) / 256;   // 6250
  const int cntB   = (E + 255) / 256;    // 2344

  hipMemsetAsync(cnt, 0, (size_t)N * sizeof(int), stream);

  cvt_count_kernel<<<cvtB + cntB, 256, 0, stream>>>(x, xb, n4, cvtB, ei, cnt, E);

  scan_a<<<SCAN_B, 256, 0, stream>>>(cnt, off, bsum, N);
  scan_b<<<1, 64, 0, stream>>>(bsum, SCAN_B);
  scan_c<<<SCAN_B, 256, 0, stream>>>(off, cur, bsum, N, E);
  fill_kernel<<<(E + 255) / 256, 256, 0, stream>>>(ei, cur, perm, E);

  edge_mlp_kernel<<<2048, 256, 0, stream>>>(xb, ei, ea, We1, be1, We2, be2, e_out, E);

  agg_kernel<<<(N + 3) / 4, 256, 0, stream>>>(e_out, off, perm, xout, N);

  const int node_tiles = (N + 63) / 64;
  node_mlp_kernel<<<node_tiles, 256, 0, stream>>>(x, Wn1, bn1, Wn2, bn2, xout, N);
}

// Round 15
// 371.995 us; speedup vs baseline: 1.1903x; 1.0126x over previous
//
#include <hip/hip_runtime.h>
#include <hip/hip_bf16.h>

#define DD 128

typedef short bf16x8 __attribute__((ext_vector_type(8)));
typedef float f32x4 __attribute__((ext_vector_type(4)));
typedef float f32x2v __attribute__((ext_vector_type(2)));

__device__ __forceinline__ unsigned short f2b(float f) {
  unsigned int u = __float_as_uint(f);
  u = u + 0x7FFFu + ((u >> 16) & 1u);
  return (unsigned short)(u >> 16);
}

// async global->LDS 16B: per-lane global src, wave-uniform LDS dest (+lane*16)
#define GLDS16(gp, lp) __builtin_amdgcn_global_load_lds( \
    (const __attribute__((address_space(1))) unsigned int*)(const void*)(gp), \
    (__attribute__((address_space(3))) unsigned int*)(void*)(lp), 16, 0, 0)

// ---------------- x f32 -> bf16 ----------------
__global__ __launch_bounds__(256) void cvt_x_kernel(const float* __restrict__ x,
                                                    unsigned short* __restrict__ xb, int n4) {
  const int i = blockIdx.x * 256 + threadIdx.x;
  if (i < n4) {
    const float4 v = reinterpret_cast<const float4*>(x)[i];
    ushort4 o;
    o.x = f2b(v.x); o.y = f2b(v.y); o.z = f2b(v.z); o.w = f2b(v.w);
    reinterpret_cast<ushort4*>(xb)[i] = o;
  }
}

// ---------------- per-node in-degree ----------------
__global__ void count_kernel(const int* __restrict__ ei, int* __restrict__ cnt, int E) {
  int i = blockIdx.x * blockDim.x + threadIdx.x;
  if (i < E) atomicAdd(&cnt[ei[E + i]], 1);
}

// ---------------- prefix scan (3 kernels) ----------------
__global__ __launch_bounds__(256) void scan_a(const int* __restrict__ cnt,
                                              int* __restrict__ off,
                                              int* __restrict__ bsum, int N) {
  __shared__ int wsum[4];
  const int t = threadIdx.x;
  const int i0 = blockIdx.x * 1024 + t * 4;
  int4 v = {0, 0, 0, 0};
  if (i0 + 3 < N) v = *reinterpret_cast<const int4*>(cnt + i0);
  else {
    if (i0 < N)     v.x = cnt[i0];
    if (i0 + 1 < N) v.y = cnt[i0 + 1];
    if (i0 + 2 < N) v.z = cnt[i0 + 2];
    if (i0 + 3 < N) v.w = cnt[i0 + 3];
  }
  const int s1 = v.x, s2 = s1 + v.y, s3 = s2 + v.z, tot = s3 + v.w;
  const int lane = t & 63, wv = t >> 6;
  int sc = tot;
#pragma unroll
  for (int d = 1; d < 64; d <<= 1) {
    int u = __shfl_up(sc, d);
    if (lane >= d) sc += u;
  }
  if (lane == 63) wsum[wv] = sc;
  __syncthreads();
  int wpre = 0;
  for (int w = 0; w < wv; ++w) wpre += wsum[w];
  const int excl = wpre + sc - tot;
  if (i0 < N)     off[i0]     = excl;
  if (i0 + 1 < N) off[i0 + 1] = excl + s1;
  if (i0 + 2 < N) off[i0 + 2] = excl + s2;
  if (i0 + 3 < N) off[i0 + 3] = excl + s3;
  if (t == 255) bsum[blockIdx.x] = wpre + sc;
}

__global__ void scan_b(int* __restrict__ bsum, int B) {
  const int t = threadIdx.x;
  const int v0 = (t < B) ? bsum[t] : 0;
  int v = v0;
#pragma unroll
  for (int d = 1; d < 64; d <<= 1) {
    int u = __shfl_up(v, d);
    if (t >= d) v += u;
  }
  if (t < B) bsum[t] = v - v0;
}

__global__ __launch_bounds__(256) void scan_c(int* __restrict__ off, int* __restrict__ cur,
                                              const int* __restrict__ bsum, int N, int E) {
  const int t = threadIdx.x;
  const int add = bsum[blockIdx.x];
  const int i0 = blockIdx.x * 1024 + t * 4;
#pragma unroll
  for (int k = 0; k < 4; ++k) {
    const int i = i0 + k;
    if (i < N) {
      const int o = off[i] + add;
      off[i] = o;
      cur[i] = o;
    }
  }
  if (blockIdx.x == 0 && t == 0) off[N] = E;
}

__global__ void fill_kernel(const int* __restrict__ ei, int* __restrict__ cur,
                            int* __restrict__ perm, int E) {
  int i = blockIdx.x * blockDim.x + threadIdx.x;
  if (i < E) {
    const int d = ei[E + i];
    const int pos = atomicAdd(&cur[d], 1);
    perm[pos] = i;
  }
}

// ---------------- edge MLP: r3/r11 body + nontemporal stream hints ----------------
// E is a multiple of 64 (600000 = 9375*64) — no tail handling.
__global__ __launch_bounds__(256, 2) void edge_mlp_kernel(
    const unsigned short* __restrict__ xb,   // [N][128] bf16
    const int* __restrict__ ei,              // [2][E]
    const float* __restrict__ ea,            // [E][128] f32
    const float* __restrict__ We1,
    const float* __restrict__ be1,
    const float* __restrict__ We2,
    const float* __restrict__ be2,
    float* __restrict__ e_out,               // [E][128] f32
    int E)
{
  // x blocks are staged by global_load_lds (linear dest, pre-swizzled source):
  // LDS[r][chunk j] holds global chunk (j ^ (r&7)); reads apply the same XOR.
  __shared__ __align__(16) unsigned short xs_lds[64][128];
  __shared__ __align__(16) unsigned short xd_lds[64][128];
  __shared__ __align__(16) unsigned short ea_lds[64][128];
  __shared__ __align__(16) unsigned short h_lds[64][136];
  __shared__ int srcs[64], dsts[64];

  const int tid  = threadIdx.x;
  const int wv   = tid >> 6;
  const int lane = tid & 63;
  const int lg   = lane >> 4;
  const int lm   = lane & 15;

  // ---- weight fragments in registers ----
  bf16x8 w1f[12][2];
  bf16x8 w2f[4][2];
  float b1[2], b2[2];
#pragma unroll
  for (int nf = 0; nf < 2; ++nf) {
    const int n = wv * 32 + nf * 16 + lm;
    b1[nf] = be1[n];
    b2[nf] = be2[n];
#pragma unroll
    for (int kb = 0; kb < 12; ++kb) {
      bf16x8 f;
#pragma unroll
      for (int j = 0; j < 8; ++j)
        f[j] = (short)f2b(We1[(kb * 32 + lg * 8 + j) * DD + n]);
      w1f[kb][nf] = f;
    }
#pragma unroll
    for (int kb = 0; kb < 4; ++kb) {
      bf16x8 f;
#pragma unroll
      for (int j = 0; j < 8; ++j)
        f[j] = (short)f2b(We2[(kb * 32 + lg * 8 + j) * DD + n]);
      w2f[kb][nf] = f;
    }
  }

  const int ntiles = E >> 6;
  for (int tile = blockIdx.x; tile < ntiles; tile += gridDim.x) {
    const int ebase = tile << 6;
    __syncthreads();  // previous tile's LDS readers done

    // ---- preload this tile's 128 indices ----
    if (tid < 64)       srcs[tid]      = ei[ebase + tid];
    else if (tid < 128) dsts[tid - 64] = ei[E + ebase + tid - 64];
    __syncthreads();

    // ---- async x gathers: each wave stages 16 rows of xs and xd ----
    {
#pragma unroll
      for (int wl = 0; wl < 4; ++wl) {
        const int r0 = wv * 16 + wl * 4;
        const int r  = r0 + (lane >> 4);
        const int ch = (lane & 15) ^ (r & 7);
        GLDS16(xb + (size_t)srcs[r] * DD + ch * 8, &xs_lds[r0][0]);
        GLDS16(xb + (size_t)dsts[r] * DD + ch * 8, &xd_lds[r0][0]);
      }
    }

    // ---- ea: nontemporal f32 stream -> bf16 -> swizzled b128 LDS writes ----
    {
      f32x4 va[4], vb[4];
#pragma unroll
      for (int it = 0; it < 4; ++it) {
        const int q = tid + it * 256;
        const int r = q >> 4;
        const int c = q & 15;
        const float* p = ea + (size_t)(ebase + r) * DD + c * 8;
        va[it] = __builtin_nontemporal_load(reinterpret_cast<const f32x4*>(p));
        vb[it] = __builtin_nontemporal_load(reinterpret_cast<const f32x4*>(p + 4));
      }
#pragma unroll
      for (int it = 0; it < 4; ++it) {
        const int q = tid + it * 256;
        const int r = q >> 4;
        const int c = q & 15;
        bf16x8 o;
        o[0] = (short)f2b(va[it][0]); o[1] = (short)f2b(va[it][1]);
        o[2] = (short)f2b(va[it][2]); o[3] = (short)f2b(va[it][3]);
        o[4] = (short)f2b(vb[it][0]); o[5] = (short)f2b(vb[it][1]);
        o[6] = (short)f2b(vb[it][2]); o[7] = (short)f2b(vb[it][3]);
        *reinterpret_cast<bf16x8*>(&ea_lds[r][(c ^ (r & 7)) * 8]) = o;
      }
    }
    __syncthreads();  // drains vmcnt (incl. global_load_lds) + lgkm

    // ---- layer 1: h = relu(A @ We1 + be1), K = 384 ----
    f32x4 acc[4][2];
#pragma unroll
    for (int mf = 0; mf < 4; ++mf)
#pragma unroll
      for (int nf = 0; nf < 2; ++nf)
        acc[mf][nf] = (f32x4){0.f, 0.f, 0.f, 0.f};

#pragma unroll
    for (int kb = 0; kb < 12; ++kb) {
      const unsigned short (*blk)[128] = (kb < 4) ? xs_lds : (kb < 8) ? xd_lds : ea_lds;
      const int kl = kb & 3;
      bf16x8 a[4];
#pragma unroll
      for (int mf = 0; mf < 4; ++mf) {
        const int r = mf * 16 + lm;
        a[mf] = *reinterpret_cast<const bf16x8*>(&blk[r][((kl * 4 + lg) ^ (r & 7)) * 8]);
      }
#pragma unroll
      for (int mf = 0; mf < 4; ++mf)
#pragma unroll
        for (int nf = 0; nf < 2; ++nf)
          acc[mf][nf] = __builtin_amdgcn_mfma_f32_16x16x32_bf16(a[mf], w1f[kb][nf], acc[mf][nf], 0, 0, 0);
    }

#pragma unroll
    for (int mf = 0; mf < 4; ++mf)
#pragma unroll
      for (int nf = 0; nf < 2; ++nf)
#pragma unroll
        for (int rg = 0; rg < 4; ++rg) {
          const int m = mf * 16 + lg * 4 + rg;
          const int n = wv * 32 + nf * 16 + lm;
          float v = acc[mf][nf][rg] + b1[nf];
          h_lds[m][n] = f2b(v > 0.f ? v : 0.f);
        }
    __syncthreads();

    // ---- layer 2: e = h @ We2 + be2 ----
    f32x4 acc2[4][2];
#pragma unroll
    for (int mf = 0; mf < 4; ++mf)
#pragma unroll
      for (int nf = 0; nf < 2; ++nf)
        acc2[mf][nf] = (f32x4){0.f, 0.f, 0.f, 0.f};

#pragma unroll
    for (int kb = 0; kb < 4; ++kb) {
      bf16x8 a[4];
#pragma unroll
      for (int mf = 0; mf < 4; ++mf)
        a[mf] = *reinterpret_cast<const bf16x8*>(&h_lds[mf * 16 + lm][kb * 32 + lg * 8]);
#pragma unroll
      for (int mf = 0; mf < 4; ++mf)
#pragma unroll
        for (int nf = 0; nf < 2; ++nf)
          acc2[mf][nf] = __builtin_amdgcn_mfma_f32_16x16x32_bf16(a[mf], w2f[kb][nf], acc2[mf][nf], 0, 0, 0);
    }

    // ---- epilogue: nontemporal e stores (write-once stream) ----
#pragma unroll
    for (int mf = 0; mf < 4; ++mf)
#pragma unroll
      for (int rg = 0; rg < 4; ++rg) {
        const int gm = ebase + mf * 16 + lg * 4 + rg;
#pragma unroll
        for (int nf = 0; nf < 2; ++nf) {
          const int n = wv * 32 + nf * 16 + lm;
          __builtin_nontemporal_store(acc2[mf][nf][rg] + b2[nf],
                                      &e_out[(size_t)gm * DD + n]);
        }
      }
  }
}

// ---------------- CSR scatter-mean: wave per node, 8-deep batched NT gathers ----
__global__ __launch_bounds__(256) void agg_kernel(const float* __restrict__ e_out,
                                                  const int* __restrict__ off,
                                                  const int* __restrict__ perm,
                                                  float* __restrict__ agg, int N) {
  const int wv   = threadIdx.x >> 6;
  const int lane = threadIdx.x & 63;
  const int nid  = blockIdx.x * 4 + wv;
  if (nid >= N) return;
  const int o0 = off[nid], o1 = off[nid + 1];
  float sx = 0.f, sy = 0.f;
  int j = o0;
  for (; j + 8 <= o1; j += 8) {
    int r[8];
#pragma unroll
    for (int k = 0; k < 8; ++k) r[k] = perm[j + k];
    f32x2v v[8];
#pragma unroll
    for (int k = 0; k < 8; ++k)
      v[k] = __builtin_nontemporal_load(
          reinterpret_cast<const f32x2v*>(e_out + (size_t)r[k] * DD + (lane << 1)));
#pragma unroll
    for (int k = 0; k < 8; ++k) { sx += v[k][0]; sy += v[k][1]; }
  }
  if (j + 4 <= o1) {
    int r[4];
#pragma unroll
    for (int k = 0; k < 4; ++k) r[k] = perm[j + k];
    f32x2v v[4];
#pragma unroll
    for (int k = 0; k < 4; ++k)
      v[k] = __builtin_nontemporal_load(
          reinterpret_cast<const f32x2v*>(e_out + (size_t)r[k] * DD + (lane << 1)));
#pragma unroll
    for (int k = 0; k < 4; ++k) { sx += v[k][0]; sy += v[k][1]; }
    j += 4;
  }
  for (; j < o1; ++j) {
    const int r = perm[j];
    const f32x2v v = __builtin_nontemporal_load(
        reinterpret_cast<const f32x2v*>(e_out + (size_t)r * DD + (lane << 1)));
    sx += v[0]; sy += v[1];
  }
  const int deg = o1 - o0;
  const float inv = deg > 0 ? 1.f / (float)deg : 0.f;
  float2 o;
  o.x = sx * inv;
  o.y = sy * inv;
  *reinterpret_cast<float2*>(agg + (size_t)nid * DD + (lane << 1)) = o;
}

// ---------------- node MLP (r11 exact) ----------------
__global__ __launch_bounds__(256, 2) void node_mlp_kernel(
    const float* __restrict__ x,
    const float* __restrict__ Wn1,
    const float* __restrict__ bn1,
    const float* __restrict__ Wn2,
    const float* __restrict__ bn2,
    float* __restrict__ xout,        // in: agg mean, out: x_out
    int N)
{
  __shared__ __align__(16) unsigned short A_lds[64][264];
  __shared__ __align__(16) unsigned short h_lds[64][136];

  const int tid  = threadIdx.x;
  const int wv   = tid >> 6;
  const int lane = tid & 63;
  const int lg   = lane >> 4;
  const int lm   = lane & 15;

  bf16x8 w1f[8][2];
  bf16x8 w2f[4][2];
  float b1[2], b2[2];
#pragma unroll
  for (int nf = 0; nf < 2; ++nf) {
    const int n = wv * 32 + nf * 16 + lm;
    b1[nf] = bn1[n];
    b2[nf] = bn2[n];
#pragma unroll
    for (int kb = 0; kb < 8; ++kb) {
      bf16x8 f;
#pragma unroll
      for (int j = 0; j < 8; ++j)
        f[j] = (short)f2b(Wn1[(kb * 32 + lg * 8 + j) * DD + n]);
      w1f[kb][nf] = f;
    }
#pragma unroll
    for (int kb = 0; kb < 4; ++kb) {
      bf16x8 f;
#pragma unroll
      for (int j = 0; j < 8; ++j)
        f[j] = (short)f2b(Wn2[(kb * 32 + lg * 8 + j) * DD + n]);
      w2f[kb][nf] = f;
    }
  }

  const int ntiles = (N + 63) >> 6;
  for (int tile = blockIdx.x; tile < ntiles; tile += gridDim.x) {
    const int nbase = tile << 6;
    __syncthreads();

#pragma unroll
    for (int it = 0; it < 16; ++it) {
      const int q = tid + it * 256;
      const int r = q >> 6;
      const int c = q & 63;
      int gr = nbase + r;
      if (gr >= N) gr = N - 1;
      float4 v;
      if (c < 32) v = *reinterpret_cast<const float4*>(x + (size_t)gr * DD + (c << 2));
      else        v = *reinterpret_cast<const float4*>(xout + (size_t)gr * DD + ((c - 32) << 2));
      unsigned short* dst = &A_lds[r][c << 2];
      dst[0] = f2b(v.x); dst[1] = f2b(v.y); dst[2] = f2b(v.z); dst[3] = f2b(v.w);
    }
    __syncthreads();

    f32x4 acc[4][2];
#pragma unroll
    for (int mf = 0; mf < 4; ++mf)
#pragma unroll
      for (int nf = 0; nf < 2; ++nf)
        acc[mf][nf] = (f32x4){0.f, 0.f, 0.f, 0.f};

#pragma unroll
    for (int kb = 0; kb < 8; ++kb) {
      bf16x8 a[4];
#pragma unroll
      for (int mf = 0; mf < 4; ++mf)
        a[mf] = *reinterpret_cast<const bf16x8*>(&A_lds[mf * 16 + lm][kb * 32 + lg * 8]);
#pragma unroll
      for (int mf = 0; mf < 4; ++mf)
#pragma unroll
        for (int nf = 0; nf < 2; ++nf)
          acc[mf][nf] = __builtin_amdgcn_mfma_f32_16x16x32_bf16(a[mf], w1f[kb][nf], acc[mf][nf], 0, 0, 0);
    }

#pragma unroll
    for (int mf = 0; mf < 4; ++mf)
#pragma unroll
      for (int nf = 0; nf < 2; ++nf)
#pragma unroll
        for (int rg = 0; rg < 4; ++rg) {
          const int m = mf * 16 + lg * 4 + rg;
          const int n = wv * 32 + nf * 16 + lm;
          float v = acc[mf][nf][rg] + b1[nf];
          h_lds[m][n] = f2b(v > 0.f ? v : 0.f);
        }
    __syncthreads();

    f32x4 acc2[4][2];
#pragma unroll
    for (int mf = 0; mf < 4; ++mf)
#pragma unroll
      for (int nf = 0; nf < 2; ++nf)
        acc2[mf][nf] = (f32x4){0.f, 0.f, 0.f, 0.f};

#pragma unroll
    for (int kb = 0; kb < 4; ++kb) {
      bf16x8 a[4];
#pragma unroll
      for (int mf = 0; mf < 4; ++mf)
        a[mf] = *reinterpret_cast<const bf16x8*>(&h_lds[mf * 16 + lm][kb * 32 + lg * 8]);
#pragma unroll
      for (int mf = 0; mf < 4; ++mf)
#pragma unroll
        for (int nf = 0; nf < 2; ++nf)
          acc2[mf][nf] = __builtin_amdgcn_mfma_f32_16x16x32_bf16(a[mf], w2f[kb][nf], acc2[mf][nf], 0, 0, 0);
    }

#pragma unroll
    for (int mf = 0; mf < 4; ++mf)
#pragma unroll
      for (int rg = 0; rg < 4; ++rg) {
        const int gm = nbase + mf * 16 + lg * 4 + rg;
        if (gm < N) {
#pragma unroll
          for (int nf = 0; nf < 2; ++nf) {
            const int n = wv * 32 + nf * 16 + lm;
            xout[(size_t)gm * DD + n] = acc2[mf][nf][rg] + b2[nf];
          }
        }
      }
  }
}

extern "C" void kernel_launch(void* const* d_in, const int* in_sizes, int n_in,
                              void* d_out, int out_size, void* d_ws, size_t ws_size,
                              hipStream_t stream) {
  const float* x   = (const float*)d_in[0];
  const int*   ei  = (const int*)d_in[1];
  const float* ea  = (const float*)d_in[2];
  const float* We1 = (const float*)d_in[3];
  const float* be1 = (const float*)d_in[4];
  const float* We2 = (const float*)d_in[5];
  const float* be2 = (const float*)d_in[6];
  const float* Wn1 = (const float*)d_in[7];
  const float* bn1 = (const float*)d_in[8];
  const float* Wn2 = (const float*)d_in[9];
  const float* bn2 = (const float*)d_in[10];

  const int N = in_sizes[0] / DD;   // 50000
  const int E = in_sizes[2] / DD;   // 600000

  float* out   = (float*)d_out;
  float* xout  = out;                    // x_out; early: x_bf16 scratch, then agg mean
  float* e_out = out + (size_t)N * DD;   // e output

  unsigned short* xb = (unsigned short*)xout;  // x as bf16 (dead after edge kernel)

  int* cnt  = (int*)d_ws;                // N
  int* off  = cnt + N;                   // N+1
  int* cur  = off + N + 1;               // N
  int* perm = cur + N;                   // E
  int* bsum = perm + E;                  // <=64

  const int SCAN_B = (N + 1023) / 1024;  // 49

  hipMemsetAsync(cnt, 0, (size_t)N * sizeof(int), stream);

  cvt_x_kernel<<<(N * DD / 4 + 255) / 256, 256, 0, stream>>>(x, xb, N * DD / 4);

  count_kernel<<<(E + 255) / 256, 256, 0, stream>>>(ei, cnt, E);
  scan_a<<<SCAN_B, 256, 0, stream>>>(cnt, off, bsum, N);
  scan_b<<<1, 64, 0, stream>>>(bsum, SCAN_B);
  scan_c<<<SCAN_B, 256, 0, stream>>>(off, cur, bsum, N, E);
  fill_kernel<<<(E + 255) / 256, 256, 0, stream>>>(ei, cur, perm, E);

  edge_mlp_kernel<<<2048, 256, 0, stream>>>(xb, ei, ea, We1, be1, We2, be2, e_out, E);

  agg_kernel<<<(N + 3) / 4, 256, 0, stream>>>(e_out, off, perm, xout, N);

  const int node_tiles = (N + 63) / 64;
  node_mlp_kernel<<<node_tiles, 256, 0, stream>>>(x, Wn1, bn1, Wn2, bn2, xout, N);
}